// Round 12
// baseline (260.487 us; speedup 1.0000x reference)
//
#include <hip/hip_runtime.h>

typedef __attribute__((ext_vector_type(8))) short short8;
typedef __attribute__((ext_vector_type(4))) float f32x4;

// Problem constants (B, D, E, S, H, Z) = (16384, 512, 16, 1, 256, 256)
constexpr int Bsz = 16384;
constexpr int Dd  = 512;
constexpr int Ee  = 16;
constexpr int Hh  = 256;
constexpr int Zz  = 256;
constexpr int BT  = 64;       // b rows per block
constexpr int WCLD = 17;      // wc padded stride
constexpr int HLD  = 544;     // hidB row stride bytes (512 + 32 pad)
// LDS: hA 64KB | hidB 34KB | wc 4.25KB
constexpr int OFF_HID = 65536;
constexpr int OFF_WC  = OFF_HID + BT * HLD;          // 100352
constexpr int SMEM_MAIN = OFF_WC + 64 * WCLD * 4;    // 104704 B

__device__ __forceinline__ unsigned short f2bf(float f) {
    unsigned u = __float_as_uint(f);
    u += 0x7FFFu + ((u >> 16) & 1u);          // round-to-nearest-even
    return (unsigned short)(u >> 16);
}

// hidB swizzled byte offset (R10/R11-validated)
__device__ __forceinline__ int hoff(int b, int h) {
    return b * HLD + ((((h) >> 3) ^ (b & 7)) << 4) + ((h & 7) << 1);
}

// T19 schedule directive, one per K=64 macro-step:
// issue the 8 next-macro weight loads FIRST, then 8 LDS B-frag reads,
// then the 32 MFMAs of the current macro. Compiler still owns all waitcnts.
#define SGB_MACRO                                                   \
    __builtin_amdgcn_sched_group_barrier(0x020, 8, 0);  /* VMEM_READ */ \
    __builtin_amdgcn_sched_group_barrier(0x100, 8, 0);  /* DS_READ   */ \
    __builtin_amdgcn_sched_group_barrier(0x008, 32, 0); /* MFMA      */

// Batched transpose + fp32->bf16: src [E][R][C] f32  ->  dst [E][C][R] bf16
__global__ void transpose_bf16(const float* __restrict__ src,
                               unsigned short* __restrict__ dst,
                               int R, int C) {
    __shared__ float tile[64][65];
    int tilesC = C >> 6, tilesR = R >> 6;
    int bid = blockIdx.x;
    int e  = bid / (tilesR * tilesC);
    int rm = bid % (tilesR * tilesC);
    int rt = rm / tilesC;
    int ct = rm % tilesC;
    int t  = threadIdx.x;
    int c  = t & 63;
    int r0 = t >> 6;
    const float* s = src + (size_t)e * R * C + (size_t)(rt * 64) * C + ct * 64;
    #pragma unroll
    for (int i = 0; i < 16; ++i) {
        int r = r0 + i * 4;
        tile[r][c] = s[(size_t)r * C + c];
    }
    __syncthreads();
    unsigned short* d = dst + (size_t)e * R * C + (size_t)(ct * 64) * R + rt * 64;
    #pragma unroll
    for (int i = 0; i < 16; ++i) {
        int r = r0 + i * 4;
        d[(size_t)r * R + c] = f2bf(tile[c][r]);
    }
}

// Fused SoftMoE, transposed-GEMM form: hidT[h][b], outT[z][b].
// 256 blocks x 256 threads (4 waves), 1 block/CU. Weights stream from
// global (L2/L3-resident) straight into registers -- no LDS round-trip.
// sched_group_barrier pins the dist-1 macro pipeline; compiler owns waits.
__global__ __launch_bounds__(256, 1) void moe_fused(
    const float* __restrict__ hptr,            // [B][512] f32
    const float* __restrict__ phi,             // [512][16] f32
    const float* __restrict__ b1,              // [16][256] f32
    const float* __restrict__ b2,              // [16][256] f32
    const unsigned short* __restrict__ w1t,    // [16][256(h)][512(d)] bf16
    const unsigned short* __restrict__ w2t,    // [16][256(z)][256(h)] bf16
    float* __restrict__ out)                   // [B][256] f32
{
    extern __shared__ char smem[];
    char*  hA   = smem;                         // [64][512] bf16, XOR-swizzled
    char*  hidB = smem + OFF_HID;               // [64 b][256 h] bf16, swizzled
    float* wc   = (float*)(smem + OFF_WC);      // [64][17] softmax

    const int t    = threadIdx.x;
    const int lane = t & 63;
    const int wv   = t >> 6;          // wave 0..3: owns h/z rows [wv*64, +64)
    const int l15  = lane & 15;
    const int lg   = lane >> 4;       // 0..3
    const int b0   = blockIdx.x * BT;

    short8 bufA[2][4], bufB[2][4];    // double-buffered weight A-frags (K=64)

    auto loadW = [&](short8 (&dst)[2][4], const unsigned short* wbase, int ldk, int kBase) {
        #pragma unroll
        for (int c = 0; c < 2; ++c)
            #pragma unroll
            for (int mi = 0; mi < 4; ++mi) {
                int row = wv * 64 + mi * 16 + l15;
                int kl  = kBase + c * 32 + lg * 8;
                dst[c][mi] = *reinterpret_cast<const short8*>(wbase + (size_t)row * ldk + kl);
            }
    };
    // acc[mi][n] += W-frag x hA-frag   (D[h][b]), K=64 macro
    auto mfma_hA = [&](short8 (&bw)[2][4], f32x4 (&acc)[4][4], int kBase) {
        #pragma unroll
        for (int c = 0; c < 2; ++c) {
            int kg = kBase + c * 32 + lg * 8;
            short8 bh[4];
            #pragma unroll
            for (int n = 0; n < 4; ++n) {
                int b = n * 16 + l15;
                bh[n] = *reinterpret_cast<const short8*>(
                    hA + (b << 10) + (((kg >> 3) ^ (b & 7)) << 4));
            }
            #pragma unroll
            for (int mi = 0; mi < 4; ++mi)
                #pragma unroll
                for (int n = 0; n < 4; ++n)
                    acc[mi][n] = __builtin_amdgcn_mfma_f32_16x16x32_bf16(
                        bw[c][mi], bh[n], acc[mi][n], 0, 0, 0);
        }
    };
    // acc[mi][n] += W-frag x hid-frag  (D[z][b]), K=64 macro
    auto mfma_hid = [&](short8 (&bw)[2][4], f32x4 (&acc)[4][4], int kBase) {
        #pragma unroll
        for (int c = 0; c < 2; ++c) {
            int kg = kBase + c * 32 + lg * 8;
            short8 bh[4];
            #pragma unroll
            for (int n = 0; n < 4; ++n) {
                int b = n * 16 + l15;
                bh[n] = *reinterpret_cast<const short8*>(
                    hidB + b * HLD + (((kg >> 3) ^ (b & 7)) << 4));
            }
            #pragma unroll
            for (int mi = 0; mi < 4; ++mi)
                #pragma unroll
                for (int n = 0; n < 4; ++n)
                    acc[mi][n] = __builtin_amdgcn_mfma_f32_16x16x32_bf16(
                        bw[c][mi], bh[n], acc[mi][n], 0, 0, 0);
        }
    };

    // prologue: expert-0 macro-0 weight frags (land under staging+gating)
    loadW(bufA, w1t, Dd, 0);

    // ---- stage h tile -> bf16 swizzled LDS ----
    {
        const f32x4* hsrc = reinterpret_cast<const f32x4*>(hptr + (size_t)b0 * Dd);
        #pragma unroll
        for (int i = 0; i < 32; ++i) {
            int idx = t + i * 256;
            int row = idx >> 7;
            int kc  = idx & 127;
            int k   = kc << 2;
            f32x4 v = hsrc[(size_t)row * 128 + kc];
            unsigned lo = (unsigned)f2bf(v.x) | ((unsigned)f2bf(v.y) << 16);
            unsigned hi = (unsigned)f2bf(v.z) | ((unsigned)f2bf(v.w) << 16);
            int byte = (row << 10) + (((k >> 3) ^ (row & 7)) << 4) + ((k & 7) << 1);
            *reinterpret_cast<uint2*>(hA + byte) = make_uint2(lo, hi);
        }
    }
    __syncthreads();

    // ---- gating via MFMA: 64x16 logits (waves redundant), wave 0 stores ----
    {
        f32x4 g[4];
        #pragma unroll
        for (int m = 0; m < 4; ++m) g[m] = (f32x4){0.f, 0.f, 0.f, 0.f};
        #pragma unroll
        for (int kc = 0; kc < 16; ++kc) {
            int kb = kc * 32 + lg * 8;
            short8 bfr;
            #pragma unroll
            for (int j = 0; j < 8; ++j)
                bfr[j] = (short)f2bf(phi[(size_t)(kb + j) * Ee + l15]);
            #pragma unroll
            for (int m = 0; m < 4; ++m) {
                int row = m * 16 + l15;
                short8 af = *reinterpret_cast<const short8*>(
                    hA + (row << 10) + (((kb >> 3) ^ (row & 7)) << 4));
                g[m] = __builtin_amdgcn_mfma_f32_16x16x32_bf16(af, bfr, g[m], 0, 0, 0);
            }
        }
        if (wv == 0) {
            #pragma unroll
            for (int m = 0; m < 4; ++m)
                #pragma unroll
                for (int j = 0; j < 4; ++j)
                    wc[(m * 16 + lg * 4 + j) * WCLD + l15] = g[m][j];
        }
    }
    __syncthreads();
    if (t < 64) {
        float w[16];
        float mx = -1e30f;
        #pragma unroll
        for (int e = 0; e < 16; ++e) { w[e] = wc[t * WCLD + e]; mx = fmaxf(mx, w[e]); }
        float s = 0.f;
        #pragma unroll
        for (int e = 0; e < 16; ++e) { w[e] = __expf(w[e] - mx); s += w[e]; }
        float inv = 1.f / s;
        #pragma unroll
        for (int e = 0; e < 16; ++e) wc[t * WCLD + e] = w[e] * inv;
    }
    __syncthreads();

    f32x4 outacc[4][4];
    #pragma unroll
    for (int mi = 0; mi < 4; ++mi)
        #pragma unroll
        for (int n = 0; n < 4; ++n) outacc[mi][n] = (f32x4){0.f, 0.f, 0.f, 0.f};

    const int hbb = wv * 64 + lg * 4;       // bias base (mi adds 16)

    const unsigned short* w1e = w1t;
    for (int e = 0; e < Ee; ++e) {
        const unsigned short* w2e = w2t + (size_t)e * Zz * Hh;
        const unsigned short* w1n = w1t + (size_t)((e + 1) & 15) * Hh * Dd;

        f32x4 hacc[4][4];
        #pragma unroll
        for (int mi = 0; mi < 4; ++mi)
            #pragma unroll
            for (int n = 0; n < 4; ++n) hacc[mi][n] = (f32x4){0.f, 0.f, 0.f, 0.f};

        // GEMM1-T: 8 macros K=64, dist-1 register pipeline, SGB-pinned
        loadW(bufB, w1e, Dd, 64);   mfma_hA(bufA, hacc, 0);    SGB_MACRO
        loadW(bufA, w1e, Dd, 128);  mfma_hA(bufB, hacc, 64);   SGB_MACRO
        loadW(bufB, w1e, Dd, 192);  mfma_hA(bufA, hacc, 128);  SGB_MACRO
        loadW(bufA, w1e, Dd, 256);  mfma_hA(bufB, hacc, 192);  SGB_MACRO
        loadW(bufB, w1e, Dd, 320);  mfma_hA(bufA, hacc, 256);  SGB_MACRO
        loadW(bufA, w1e, Dd, 384);  mfma_hA(bufB, hacc, 320);  SGB_MACRO
        loadW(bufB, w1e, Dd, 448);  mfma_hA(bufA, hacc, 384);  SGB_MACRO
        loadW(bufA, w2e, Hh, 0);    mfma_hA(bufB, hacc, 448);  SGB_MACRO

        // per-expert bias (compiler places/waits; outside SGB groups)
        f32x4 b1v[4];
        #pragma unroll
        for (int mi = 0; mi < 4; ++mi)
            b1v[mi] = *reinterpret_cast<const f32x4*>(b1 + (size_t)e * Hh + hbb + mi * 16);

        // all waves done reading hidB (prev expert GEMM2) before overwriting
        asm volatile("s_waitcnt lgkmcnt(0)\n\ts_barrier" ::: "memory");

        // epilogue1-T: v = relu(hid + b1)*c[b,e] -> bf16 hidB
        #pragma unroll
        for (int mi = 0; mi < 4; ++mi) {
            int hb = hbb + mi * 16;
            #pragma unroll
            for (int n = 0; n < 4; ++n) {
                int b = n * 16 + l15;
                float cbe = wc[b * WCLD + e];
                float v0 = fmaxf(hacc[mi][n][0] + b1v[mi][0], 0.f) * cbe;
                float v1 = fmaxf(hacc[mi][n][1] + b1v[mi][1], 0.f) * cbe;
                float v2 = fmaxf(hacc[mi][n][2] + b1v[mi][2], 0.f) * cbe;
                float v3 = fmaxf(hacc[mi][n][3] + b1v[mi][3], 0.f) * cbe;
                unsigned lo = (unsigned)f2bf(v0) | ((unsigned)f2bf(v1) << 16);
                unsigned hi = (unsigned)f2bf(v2) | ((unsigned)f2bf(v3) << 16);
                *reinterpret_cast<uint2*>(hidB + hoff(b, hb)) = make_uint2(lo, hi);
            }
        }
        asm volatile("s_waitcnt lgkmcnt(0)\n\ts_barrier" ::: "memory");

        // GEMM2-T: 4 macros K=64 (macro-0 weights issued in GEMM1's tail)
        loadW(bufB, w2e, Hh, 64);   mfma_hid(bufA, outacc, 0);    SGB_MACRO
        loadW(bufA, w2e, Hh, 128);  mfma_hid(bufB, outacc, 64);   SGB_MACRO
        loadW(bufB, w2e, Hh, 192);  mfma_hid(bufA, outacc, 128);  SGB_MACRO
        loadW(bufA, w1n, Dd, 0);    mfma_hid(bufB, outacc, 192);  SGB_MACRO

        w1e = w1n;
    }

    // ---- final epilogue: out[b][z] = outT[z][b] + sum_e c[b,e]*b2[e,z] ----
    {
        int zb = wv * 64 + lg * 4;          // mi adds 16
        #pragma unroll
        for (int e = 0; e < 16; ++e) {
            float cbe[4];
            #pragma unroll
            for (int n = 0; n < 4; ++n) cbe[n] = wc[(n * 16 + l15) * WCLD + e];
            #pragma unroll
            for (int mi = 0; mi < 4; ++mi) {
                f32x4 b2v = *reinterpret_cast<const f32x4*>(
                    b2 + (size_t)e * Zz + zb + mi * 16);
                #pragma unroll
                for (int n = 0; n < 4; ++n) outacc[mi][n] += cbe[n] * b2v;
            }
        }
        #pragma unroll
        for (int mi = 0; mi < 4; ++mi) {
            #pragma unroll
            for (int n = 0; n < 4; ++n) {
                int b = b0 + n * 16 + l15;
                *reinterpret_cast<f32x4*>(out + (size_t)b * Zz + zb + mi * 16) =
                    outacc[mi][n];
            }
        }
    }
}

extern "C" void kernel_launch(void* const* d_in, const int* in_sizes, int n_in,
                              void* d_out, int out_size, void* d_ws, size_t ws_size,
                              hipStream_t stream) {
    const float* h   = (const float*)d_in[0];
    const float* phi = (const float*)d_in[1];
    const float* W1  = (const float*)d_in[2];
    const float* b1  = (const float*)d_in[3];
    const float* W2  = (const float*)d_in[4];
    const float* b2  = (const float*)d_in[5];
    float* out = (float*)d_out;

    unsigned short* w1t = (unsigned short*)d_ws;                      // 4 MB
    unsigned short* w2t = w1t + (size_t)Ee * Hh * Dd;                 // 2 MB

    (void)hipFuncSetAttribute((const void*)moe_fused,
                              hipFuncAttributeMaxDynamicSharedMemorySize, SMEM_MAIN);

    transpose_bf16<<<Ee * (Dd / 64) * (Hh / 64), 256, 0, stream>>>(W1, w1t, Dd, Hh);
    transpose_bf16<<<Ee * (Hh / 64) * (Zz / 64), 256, 0, stream>>>(W2, w2t, Hh, Zz);

    moe_fused<<<Bsz / BT, 256, SMEM_MAIN, stream>>>(h, phi, b1, b2, w1t, w2t, out);
}

// Round 13
// 146.590 us; speedup vs baseline: 1.7770x; 1.7770x over previous
//
#include <hip/hip_runtime.h>

typedef __attribute__((ext_vector_type(8))) short short8;
typedef __attribute__((ext_vector_type(4))) float f32x4;

// Problem constants (B, D, E, S, H, Z) = (16384, 512, 16, 1, 256, 256)
constexpr int Bsz = 16384;
constexpr int Dd  = 512;
constexpr int Ee  = 16;
constexpr int Hh  = 256;
constexpr int Zz  = 256;
constexpr int BT  = 64;       // b rows per block
constexpr int WCLD = 17;      // wc padded stride
constexpr int HLD  = 544;     // hidB row stride bytes (512 + 32 pad)
constexpr int CHK  = 16384;   // weight chunk: 256 rows x 32 k bf16 = 16KB
// LDS: hA 64KB | per-wave triple bufs 4x3x4KB | hidB 34KB | wc 4.25KB | b1 1KB
constexpr int OFF_P   = 65536;
constexpr int OFF_HID = OFF_P + 4 * 3 * 4096;        // 114688
constexpr int OFF_WC  = OFF_HID + BT * HLD;          // 149504
constexpr int OFF_B1  = OFF_WC + 64 * WCLD * 4;      // 153856
constexpr int SMEM_MAIN = OFF_B1 + 1024;             // 154880 B

// counted per-wave vmcnt wait; memory clobber orders following ds_reads
#define WAITV(N) asm volatile("s_waitcnt vmcnt(" #N ")" ::: "memory")

__device__ __forceinline__ unsigned short f2bf(float f) {
    unsigned u = __float_as_uint(f);
    u += 0x7FFFu + ((u >> 16) & 1u);          // round-to-nearest-even
    return (unsigned short)(u >> 16);
}

// hidB swizzled byte offset (R10/R11-validated)
__device__ __forceinline__ int hoff(int b, int h) {
    return b * HLD + ((((h) >> 3) ^ (b & 7)) << 4) + ((h & 7) << 1);
}

// packed-weight byte offset: chunk 16KB | row*64 | col XOR | k&7 (R11-validated)
__device__ __forceinline__ size_t woff(int row, int k) {
    return (size_t)(k >> 5) * CHK + (size_t)row * 64 +
           ((((k >> 3) & 3) ^ ((row >> 1) & 3)) << 4) + ((k & 7) << 1);
}

// stage this wave's private 4KB slice of a 16KB chunk (4 x 1KB loads)
__device__ __forceinline__ void stage4(const char* chunkBase, char* ldsbuf,
                                       int wv, int lane) {
    const char* g = chunkBase + wv * 4096 + lane * 16;
    #pragma unroll
    for (int r = 0; r < 4; ++r)
        __builtin_amdgcn_global_load_lds(
            (const __attribute__((address_space(1))) void*)(g + r * 1024),
            (__attribute__((address_space(3))) void*)(ldsbuf + r * 1024), 16, 0, 0);
}

// Transpose + fp32->bf16 + pack into the chunked/swizzled image
__global__ void transpose_pack(const float* __restrict__ src,
                               unsigned short* __restrict__ dst,
                               int R, int C) {
    __shared__ float tile[64][65];
    int tilesC = C >> 6, tilesR = R >> 6;
    int bid = blockIdx.x;
    int e  = bid / (tilesR * tilesC);
    int rm = bid % (tilesR * tilesC);
    int rt = rm / tilesC;
    int ct = rm % tilesC;
    int t  = threadIdx.x;
    int c  = t & 63;
    int r0 = t >> 6;
    const float* s = src + (size_t)e * R * C + (size_t)(rt * 64) * C + ct * 64;
    #pragma unroll
    for (int i = 0; i < 16; ++i) {
        int r = r0 + i * 4;
        tile[r][c] = s[(size_t)r * C + c];
    }
    __syncthreads();
    char* dbase = (char*)dst + (size_t)e * R * C * 2;
    #pragma unroll
    for (int i = 0; i < 16; ++i) {
        int r = r0 + i * 4;
        int row_g = ct * 64 + r;        // output row (C-dim)
        int k_g   = rt * 64 + c;        // k (R-dim)
        *reinterpret_cast<unsigned short*>(dbase + woff(row_g, k_g)) =
            f2bf(tile[c][r]);
    }
}

// Fused SoftMoE, transposed-GEMM form: hidT[h][b], outT[z][b].
// 256 blocks x 256 threads (4 waves), 1 block/CU. R11 structure plus a
// fragment-register double-buffer: per chunk, MFMA half -> counted wait ->
// ds_read next chunk's frags -> MFMA half (hides ds latency under MFMA).
__global__ __launch_bounds__(256, 1) void moe_fused(
    const float* __restrict__ hptr,            // [B][512] f32
    const float* __restrict__ phi,             // [512][16] f32
    const float* __restrict__ b1,              // [16][256] f32
    const float* __restrict__ b2,              // [16][256] f32
    const char* __restrict__ w1c,              // packed W1, 256KB/expert
    const char* __restrict__ w2c,              // packed W2, 128KB/expert
    float* __restrict__ out)                   // [B][256] f32
{
    extern __shared__ char smem[];
    char*  hA   = smem;                         // [64][512] bf16, XOR-swizzled
    char*  hidB = smem + OFF_HID;               // [64 b][256 h] bf16, swizzled
    float* wc   = (float*)(smem + OFF_WC);      // [64][17] softmax

    const int t    = threadIdx.x;
    const int lane = t & 63;
    const int wv   = t >> 6;          // wave 0..3: owns h/z rows [wv*64, +64)
    const int l15  = lane & 15;
    const int lg   = lane >> 4;       // 0..3
    const int b0   = blockIdx.x * BT;
    const int csb  = (l15 >> 1) & 3;  // weight col-swizzle base

    char* pw = smem + OFF_P + wv * 12288;       // this wave's 3 x 4KB buffers

    // double-buffered fragment registers (chunk n lives in set n&1)
    short8 awA[4], bhA[4], awB[4], bhB[4];

    auto readAW = [&](short8 (&aw)[4], const char* pb) {
        #pragma unroll
        for (int mi = 0; mi < 4; ++mi) {
            int rp = mi * 16 + l15;
            aw[mi] = *reinterpret_cast<const short8*>(
                pb + rp * 64 + ((lg ^ csb) << 4));
        }
    };
    auto readBH_hA = [&](short8 (&bh)[4], int kbase) {
        int kg = kbase + lg * 8;
        #pragma unroll
        for (int n = 0; n < 4; ++n) {
            int b = n * 16 + l15;
            bh[n] = *reinterpret_cast<const short8*>(
                hA + (b << 10) + (((kg >> 3) ^ (b & 7)) << 4));
        }
    };
    auto readBH_hid = [&](short8 (&bh)[4], int kbase) {
        int kg = kbase + lg * 8;
        #pragma unroll
        for (int n = 0; n < 4; ++n) {
            int b = n * 16 + l15;
            bh[n] = *reinterpret_cast<const short8*>(
                hidB + b * HLD + (((kg >> 3) ^ (b & 7)) << 4));
        }
    };

    // prologue: stage expert-0 chunks 0,1 (land during h-staging + gating)
    stage4(w1c, pw, wv, lane);
    stage4(w1c + CHK, pw + 4096, wv, lane);

    // ---- stage h tile -> bf16 swizzled LDS ----
    {
        const f32x4* hsrc = reinterpret_cast<const f32x4*>(hptr + (size_t)b0 * Dd);
        #pragma unroll
        for (int i = 0; i < 32; ++i) {
            int idx = t + i * 256;
            int row = idx >> 7;
            int kc  = idx & 127;
            int k   = kc << 2;
            f32x4 v = hsrc[(size_t)row * 128 + kc];
            unsigned lo = (unsigned)f2bf(v.x) | ((unsigned)f2bf(v.y) << 16);
            unsigned hi = (unsigned)f2bf(v.z) | ((unsigned)f2bf(v.w) << 16);
            int byte = (row << 10) + (((k >> 3) ^ (row & 7)) << 4) + ((k & 7) << 1);
            *reinterpret_cast<uint2*>(hA + byte) = make_uint2(lo, hi);
        }
    }
    __syncthreads();

    // ---- gating via MFMA: 64x16 logits (waves redundant), wave 0 stores ----
    {
        f32x4 g[4];
        #pragma unroll
        for (int m = 0; m < 4; ++m) g[m] = (f32x4){0.f, 0.f, 0.f, 0.f};
        #pragma unroll
        for (int kc = 0; kc < 16; ++kc) {
            int kb = kc * 32 + lg * 8;
            short8 bfr;
            #pragma unroll
            for (int j = 0; j < 8; ++j)
                bfr[j] = (short)f2bf(phi[(size_t)(kb + j) * Ee + l15]);
            #pragma unroll
            for (int m = 0; m < 4; ++m) {
                int row = m * 16 + l15;
                short8 af = *reinterpret_cast<const short8*>(
                    hA + (row << 10) + (((kb >> 3) ^ (row & 7)) << 4));
                g[m] = __builtin_amdgcn_mfma_f32_16x16x32_bf16(af, bfr, g[m], 0, 0, 0);
            }
        }
        if (wv == 0) {
            #pragma unroll
            for (int m = 0; m < 4; ++m)
                #pragma unroll
                for (int j = 0; j < 4; ++j)
                    wc[(m * 16 + lg * 4 + j) * WCLD + l15] = g[m][j];
        }
    }
    __syncthreads();
    if (t < 64) {
        float w[16];
        float mx = -1e30f;
        #pragma unroll
        for (int e = 0; e < 16; ++e) { w[e] = wc[t * WCLD + e]; mx = fmaxf(mx, w[e]); }
        float s = 0.f;
        #pragma unroll
        for (int e = 0; e < 16; ++e) { w[e] = __expf(w[e] - mx); s += w[e]; }
        float inv = 1.f / s;
        #pragma unroll
        for (int e = 0; e < 16; ++e) wc[t * WCLD + e] = w[e] * inv;
    }
    __syncthreads();

    f32x4 outacc[4][4];
    #pragma unroll
    for (int mi = 0; mi < 4; ++mi)
        #pragma unroll
        for (int n = 0; n < 4; ++n) outacc[mi][n] = (f32x4){0.f, 0.f, 0.f, 0.f};

    const char* w1e = w1c;
    for (int e = 0; e < Ee; ++e) {
        const char* w2e = w2c + (size_t)e * (Hh * Hh * 2);
        const char* w1n = w1c + (size_t)((e + 1) & 15) * (Hh * Dd * 2);

        // b1 -> LDS (adds 1 to queue; folded into iter-0's wait)
        __builtin_amdgcn_global_load_lds(
            (const __attribute__((address_space(1))) void*)(b1 + (size_t)e * Hh + wv * 64 + lane),
            (__attribute__((address_space(3))) void*)(smem + OFF_B1 + wv * 256), 4, 0, 0);

        if (e == 0) {
            // queue [c0,c1,b1]=9 -> complete c0; pre-read c0 frags
            WAITV(5);
            readAW(awA, pw);
            readBH_hA(bhA, 0);
        }
        // for e>0: c0 frags pre-read at previous expert's GEMM2 tail

        f32x4 hacc[4][4];
        #pragma unroll
        for (int mi = 0; mi < 4; ++mi)
            #pragma unroll
            for (int n = 0; n < 4; ++n) hacc[mi][n] = (f32x4){0.f, 0.f, 0.f, 0.f};

        auto mfmaHalf1 = [&](short8 (&aw)[4], short8 (&bh)[4], f32x4 (&acc)[4][4]) {
            #pragma unroll
            for (int mi = 0; mi < 2; ++mi)
                #pragma unroll
                for (int n = 0; n < 4; ++n)
                    acc[mi][n] = __builtin_amdgcn_mfma_f32_16x16x32_bf16(
                        aw[mi], bh[n], acc[mi][n], 0, 0, 0);
        };
        auto mfmaHalf2 = [&](short8 (&aw)[4], short8 (&bh)[4], f32x4 (&acc)[4][4]) {
            #pragma unroll
            for (int mi = 2; mi < 4; ++mi)
                #pragma unroll
                for (int n = 0; n < 4; ++n)
                    acc[mi][n] = __builtin_amdgcn_mfma_f32_16x16x32_bf16(
                        aw[mi], bh[n], acc[mi][n], 0, 0, 0);
        };

        // GEMM1-T iteration: MFMA chunk ci (frags in C regs), stage ci+2,
        // wait ci+1 resident, read ci+1 frags into N regs.
        auto g1iter = [&](int ci, short8 (&awC)[4], short8 (&bhC)[4],
                          short8 (&awN)[4], short8 (&bhN)[4]) {
            const char* nsrc = (ci + 2 < 16) ? (w1e + (ci + 2) * CHK)
                                             : (w2e + (ci - 14) * CHK);
            stage4(nsrc, pw + ((ci + 2) % 3) * 4096, wv, lane);
            mfmaHalf1(awC, bhC, hacc);
            WAITV(4);                               // chunk ci+1 resident
            readAW(awN, pw + ((ci + 1) % 3) * 4096);
            if (ci < 15) readBH_hA(bhN, (ci + 1) * 32);
            // ci==15: next is g0; its bh comes from hidB AFTER the barrier
            mfmaHalf2(awC, bhC, hacc);
        };
        #pragma unroll
        for (int c2 = 0; c2 < 16; c2 += 2) {
            g1iter(c2,     awA, bhA, awB, bhB);
            g1iter(c2 + 1, awB, bhB, awA, bhA);
        }

        // all waves done reading hidB (prev expert GEMM2) before overwriting
        asm volatile("s_barrier" ::: "memory");

        // epilogue1-T: v = relu(hid + b1)*c[b,e] -> bf16 hidB (b1 from LDS)
        {
            const float* b1w = (const float*)(smem + OFF_B1) + wv * 64;
            int hb0 = wv * 64 + lg * 4;
            #pragma unroll
            for (int mi = 0; mi < 4; ++mi) {
                int hb = hb0 + mi * 16;
                f32x4 b1v = *reinterpret_cast<const f32x4*>(b1w + lg * 4 + mi * 16);
                #pragma unroll
                for (int n = 0; n < 4; ++n) {
                    int b = n * 16 + l15;
                    float cbe = wc[b * WCLD + e];
                    float v0 = fmaxf(hacc[mi][n][0] + b1v[0], 0.f) * cbe;
                    float v1 = fmaxf(hacc[mi][n][1] + b1v[1], 0.f) * cbe;
                    float v2 = fmaxf(hacc[mi][n][2] + b1v[2], 0.f) * cbe;
                    float v3 = fmaxf(hacc[mi][n][3] + b1v[3], 0.f) * cbe;
                    unsigned lo = (unsigned)f2bf(v0) | ((unsigned)f2bf(v1) << 16);
                    unsigned hi = (unsigned)f2bf(v2) | ((unsigned)f2bf(v3) << 16);
                    *reinterpret_cast<uint2*>(hidB + hoff(b, hb)) = make_uint2(lo, hi);
                }
            }
        }
        asm volatile("s_waitcnt lgkmcnt(0)\n\ts_barrier" ::: "memory");

        // g0's bh (hidB) now readable; aw(g0) already in awA from iter 15
        readBH_hid(bhA, 0);

        // GEMM2-T iteration j: MFMA g_j, stage g(j+2), read g(j+1) frags.
        // j==7 prefetches next expert's c0 frags (bh from persistent hA).
        auto g2iter = [&](int j, short8 (&awC)[4], short8 (&bhC)[4],
                          short8 (&awN)[4], short8 (&bhN)[4]) {
            const char* nsrc = (j + 2 < 8) ? (w2e + (j + 2) * CHK)
                                           : (w1n + (j - 6) * CHK);
            stage4(nsrc, pw + ((16 + j + 2) % 3) * 4096, wv, lane);
            mfmaHalf1(awC, bhC, outacc);
            WAITV(4);                               // chunk g(j+1) resident
            readAW(awN, pw + ((16 + j + 1) % 3) * 4096);
            if (j < 7) readBH_hid(bhN, (j + 1) * 32);
            else       readBH_hA(bhN, 0);           // next expert c0
            mfmaHalf2(awC, bhC, outacc);
        };
        #pragma unroll
        for (int j2 = 0; j2 < 8; j2 += 2) {
            g2iter(j2,     awA, bhA, awB, bhB);
            g2iter(j2 + 1, awB, bhB, awA, bhA);
        }

        w1e = w1n;
    }

    // ---- final epilogue: out[b][z] = outT[z][b] + sum_e c[b,e]*b2[e,z] ----
    {
        int zb = wv * 64 + lg * 4;          // mi adds 16
        #pragma unroll
        for (int e = 0; e < 16; ++e) {
            float cbe[4];
            #pragma unroll
            for (int n = 0; n < 4; ++n) cbe[n] = wc[(n * 16 + l15) * WCLD + e];
            #pragma unroll
            for (int mi = 0; mi < 4; ++mi) {
                f32x4 b2v = *reinterpret_cast<const f32x4*>(
                    b2 + (size_t)e * Zz + zb + mi * 16);
                #pragma unroll
                for (int n = 0; n < 4; ++n) outacc[mi][n] += cbe[n] * b2v;
            }
        }
        #pragma unroll
        for (int mi = 0; mi < 4; ++mi) {
            #pragma unroll
            for (int n = 0; n < 4; ++n) {
                int b = b0 + n * 16 + l15;
                *reinterpret_cast<f32x4*>(out + (size_t)b * Zz + zb + mi * 16) =
                    outacc[mi][n];
            }
        }
    }
    // drain dangling wrap-around prefetches before wave exit
    asm volatile("s_waitcnt vmcnt(0)" ::: "memory");
}

extern "C" void kernel_launch(void* const* d_in, const int* in_sizes, int n_in,
                              void* d_out, int out_size, void* d_ws, size_t ws_size,
                              hipStream_t stream) {
    const float* h   = (const float*)d_in[0];
    const float* phi = (const float*)d_in[1];
    const float* W1  = (const float*)d_in[2];
    const float* b1  = (const float*)d_in[3];
    const float* W2  = (const float*)d_in[4];
    const float* b2  = (const float*)d_in[5];
    float* out = (float*)d_out;

    unsigned short* w1p = (unsigned short*)d_ws;                      // 4 MB packed
    unsigned short* w2p = w1p + (size_t)Ee * Hh * Dd;                 // 2 MB packed

    (void)hipFuncSetAttribute((const void*)moe_fused,
                              hipFuncAttributeMaxDynamicSharedMemorySize, SMEM_MAIN);

    transpose_pack<<<Ee * (Dd / 64) * (Hh / 64), 256, 0, stream>>>(W1, w1p, Dd, Hh);
    transpose_pack<<<Ee * (Hh / 64) * (Zz / 64), 256, 0, stream>>>(W2, w2p, Hh, Zz);

    moe_fused<<<Bsz / BT, 256, SMEM_MAIN, stream>>>(
        h, phi, b1, b2, (const char*)w1p, (const char*)w2p, out);
}

// Round 14
// 132.331 us; speedup vs baseline: 1.9684x; 1.1077x over previous
//
#include <hip/hip_runtime.h>

typedef __attribute__((ext_vector_type(8))) short short8;
typedef __attribute__((ext_vector_type(4))) float f32x4;

// Problem constants (B, D, E, S, H, Z) = (16384, 512, 16, 1, 256, 256)
constexpr int Bsz = 16384;
constexpr int Dd  = 512;
constexpr int Ee  = 16;
constexpr int Hh  = 256;
constexpr int Zz  = 256;
constexpr int BT  = 64;       // b rows per block
constexpr int WCLD = 17;      // wc padded stride
constexpr int HLD  = 544;     // hidB row stride bytes (512 + 32 pad)
constexpr int CHK  = 16384;   // weight chunk: 256 rows x 32 k bf16 = 16KB
// LDS: hA 64KB | per-wave triple bufs 4x3x4KB | hidB 34KB | wc 4.25KB | b1 1KB
constexpr int OFF_P   = 65536;
constexpr int OFF_HID = OFF_P + 4 * 3 * 4096;        // 114688
constexpr int OFF_WC  = OFF_HID + BT * HLD;          // 149504
constexpr int OFF_B1  = OFF_WC + 64 * WCLD * 4;      // 153856
constexpr int SMEM_MAIN = OFF_B1 + 1024;             // 154880 B

// counted per-wave vmcnt wait; memory clobber orders following ds_reads
#define WAITV(N) asm volatile("s_waitcnt vmcnt(" #N ")" ::: "memory")

__device__ __forceinline__ unsigned short f2bf(float f) {
    unsigned u = __float_as_uint(f);
    u += 0x7FFFu + ((u >> 16) & 1u);          // round-to-nearest-even
    return (unsigned short)(u >> 16);
}

// hidB swizzled byte offset (R10/R11-validated)
__device__ __forceinline__ int hoff(int b, int h) {
    return b * HLD + ((((h) >> 3) ^ (b & 7)) << 4) + ((h & 7) << 1);
}

// packed-weight byte offset: chunk 16KB | row*64 | col XOR | k&7 (R11-validated)
__device__ __forceinline__ size_t woff(int row, int k) {
    return (size_t)(k >> 5) * CHK + (size_t)row * 64 +
           ((((k >> 3) & 3) ^ ((row >> 1) & 3)) << 4) + ((k & 7) << 1);
}

// stage this wave's private 4KB slice of a 16KB chunk (4 x 1KB loads)
__device__ __forceinline__ void stage4(const char* chunkBase, char* ldsbuf,
                                       int wv, int lane) {
    const char* g = chunkBase + wv * 4096 + lane * 16;
    #pragma unroll
    for (int r = 0; r < 4; ++r)
        __builtin_amdgcn_global_load_lds(
            (const __attribute__((address_space(1))) void*)(g + r * 1024),
            (__attribute__((address_space(3))) void*)(ldsbuf + r * 1024), 16, 0, 0);
}

// Transpose + fp32->bf16 + pack into the chunked/swizzled image
__global__ void transpose_pack(const float* __restrict__ src,
                               unsigned short* __restrict__ dst,
                               int R, int C) {
    __shared__ float tile[64][65];
    int tilesC = C >> 6, tilesR = R >> 6;
    int bid = blockIdx.x;
    int e  = bid / (tilesR * tilesC);
    int rm = bid % (tilesR * tilesC);
    int rt = rm / tilesC;
    int ct = rm % tilesC;
    int t  = threadIdx.x;
    int c  = t & 63;
    int r0 = t >> 6;
    const float* s = src + (size_t)e * R * C + (size_t)(rt * 64) * C + ct * 64;
    #pragma unroll
    for (int i = 0; i < 16; ++i) {
        int r = r0 + i * 4;
        tile[r][c] = s[(size_t)r * C + c];
    }
    __syncthreads();
    char* dbase = (char*)dst + (size_t)e * R * C * 2;
    #pragma unroll
    for (int i = 0; i < 16; ++i) {
        int r = r0 + i * 4;
        int row_g = ct * 64 + r;        // output row (C-dim)
        int k_g   = rt * 64 + c;        // k (R-dim)
        *reinterpret_cast<unsigned short*>(dbase + woff(row_g, k_g)) =
            f2bf(tile[c][r]);
    }
}

// Fused SoftMoE, transposed-GEMM form: hidT[h][b], outT[z][b].
// 256 blocks x 256 threads (4 waves), 1 block/CU. R11 structure (free-running
// wave-private staged chunks, dist-2 counted vmcnt, no K-loop barriers)
// + T5: s_setprio(1) around each chunk's MFMA cluster so the CU scheduler
// favors MFMA-entering waves over stage/read-issuing waves on the LDS pipe.
__global__ __launch_bounds__(256, 1) void moe_fused(
    const float* __restrict__ hptr,            // [B][512] f32
    const float* __restrict__ phi,             // [512][16] f32
    const float* __restrict__ b1,              // [16][256] f32
    const float* __restrict__ b2,              // [16][256] f32
    const char* __restrict__ w1c,              // packed W1, 256KB/expert
    const char* __restrict__ w2c,              // packed W2, 128KB/expert
    float* __restrict__ out)                   // [B][256] f32
{
    extern __shared__ char smem[];
    char*  hA   = smem;                         // [64][512] bf16, XOR-swizzled
    char*  hidB = smem + OFF_HID;               // [64 b][256 h] bf16, swizzled
    float* wc   = (float*)(smem + OFF_WC);      // [64][17] softmax

    const int t    = threadIdx.x;
    const int lane = t & 63;
    const int wv   = t >> 6;          // wave 0..3: owns h/z rows [wv*64, +64)
    const int l15  = lane & 15;
    const int lg   = lane >> 4;       // 0..3
    const int b0   = blockIdx.x * BT;
    const int csb  = (l15 >> 1) & 3;  // weight col-swizzle base

    char* pw = smem + OFF_P + wv * 12288;       // this wave's 3 x 4KB buffers

    // prologue: stage expert-0 chunks 0,1 (land during h-staging + gating)
    stage4(w1c, pw, wv, lane);
    stage4(w1c + CHK, pw + 4096, wv, lane);

    // ---- stage h tile -> bf16 swizzled LDS ----
    {
        const f32x4* hsrc = reinterpret_cast<const f32x4*>(hptr + (size_t)b0 * Dd);
        #pragma unroll
        for (int i = 0; i < 32; ++i) {
            int idx = t + i * 256;
            int row = idx >> 7;
            int kc  = idx & 127;
            int k   = kc << 2;
            f32x4 v = hsrc[(size_t)row * 128 + kc];
            unsigned lo = (unsigned)f2bf(v.x) | ((unsigned)f2bf(v.y) << 16);
            unsigned hi = (unsigned)f2bf(v.z) | ((unsigned)f2bf(v.w) << 16);
            int byte = (row << 10) + (((k >> 3) ^ (row & 7)) << 4) + ((k & 7) << 1);
            *reinterpret_cast<uint2*>(hA + byte) = make_uint2(lo, hi);
        }
    }
    __syncthreads();

    // ---- gating via MFMA: 64x16 logits (waves redundant), wave 0 stores ----
    {
        f32x4 g[4];
        #pragma unroll
        for (int m = 0; m < 4; ++m) g[m] = (f32x4){0.f, 0.f, 0.f, 0.f};
        #pragma unroll
        for (int kc = 0; kc < 16; ++kc) {
            int kb = kc * 32 + lg * 8;
            short8 bfr;
            #pragma unroll
            for (int j = 0; j < 8; ++j)
                bfr[j] = (short)f2bf(phi[(size_t)(kb + j) * Ee + l15]);
            #pragma unroll
            for (int m = 0; m < 4; ++m) {
                int row = m * 16 + l15;
                short8 af = *reinterpret_cast<const short8*>(
                    hA + (row << 10) + (((kb >> 3) ^ (row & 7)) << 4));
                g[m] = __builtin_amdgcn_mfma_f32_16x16x32_bf16(af, bfr, g[m], 0, 0, 0);
            }
        }
        if (wv == 0) {
            #pragma unroll
            for (int m = 0; m < 4; ++m)
                #pragma unroll
                for (int j = 0; j < 4; ++j)
                    wc[(m * 16 + lg * 4 + j) * WCLD + l15] = g[m][j];
        }
    }
    __syncthreads();
    if (t < 64) {
        float w[16];
        float mx = -1e30f;
        #pragma unroll
        for (int e = 0; e < 16; ++e) { w[e] = wc[t * WCLD + e]; mx = fmaxf(mx, w[e]); }
        float s = 0.f;
        #pragma unroll
        for (int e = 0; e < 16; ++e) { w[e] = __expf(w[e] - mx); s += w[e]; }
        float inv = 1.f / s;
        #pragma unroll
        for (int e = 0; e < 16; ++e) wc[t * WCLD + e] = w[e] * inv;
    }
    __syncthreads();

    f32x4 outacc[4][4];
    #pragma unroll
    for (int mi = 0; mi < 4; ++mi)
        #pragma unroll
        for (int n = 0; n < 4; ++n) outacc[mi][n] = (f32x4){0.f, 0.f, 0.f, 0.f};

    const char* w1e = w1c;
    for (int e = 0; e < Ee; ++e) {
        const char* w2e = w2c + (size_t)e * (Hh * Hh * 2);
        const char* w1n = w1c + (size_t)((e + 1) & 15) * (Hh * Dd * 2);

        // b1 -> LDS (adds 1 to queue; folded into iter-0/1 waits)
        __builtin_amdgcn_global_load_lds(
            (const __attribute__((address_space(1))) void*)(b1 + (size_t)e * Hh + wv * 64 + lane),
            (__attribute__((address_space(3))) void*)(smem + OFF_B1 + wv * 256), 4, 0, 0);

        f32x4 hacc[4][4];
        #pragma unroll
        for (int mi = 0; mi < 4; ++mi)
            #pragma unroll
            for (int n = 0; n < 4; ++n) hacc[mi][n] = (f32x4){0.f, 0.f, 0.f, 0.f};

        // GEMM1-T: 16 chunks K=32, dist-2, wave-private, barrier-free.
        // Ledger: iter0 [c0,c1,b1,c2]=13 wait 9; iter1 13 wait 9;
        //         iter2 [b1,c2,c3,c4]=13 wait 8 (b1 done); steady 12 wait 8.
        #pragma unroll
        for (int ci = 0; ci < 16; ++ci) {
            const char* nsrc = (ci + 2 < 16) ? (w1e + (ci + 2) * CHK)
                                             : (w2e + (ci - 14) * CHK);
            stage4(nsrc, pw + ((ci + 2) % 3) * 4096, wv, lane);
            if (ci < 2) { WAITV(9); } else { WAITV(8); }
            const char* pb = pw + (ci % 3) * 4096;
            short8 aw[4], bh[4];
            #pragma unroll
            for (int mi = 0; mi < 4; ++mi) {
                int rp = mi * 16 + l15;
                aw[mi] = *reinterpret_cast<const short8*>(
                    pb + rp * 64 + ((lg ^ csb) << 4));
            }
            int kg = ci * 32 + lg * 8;
            #pragma unroll
            for (int n = 0; n < 4; ++n) {
                int b = n * 16 + l15;
                bh[n] = *reinterpret_cast<const short8*>(
                    hA + (b << 10) + (((kg >> 3) ^ (b & 7)) << 4));
            }
            __builtin_amdgcn_s_setprio(1);
            #pragma unroll
            for (int mi = 0; mi < 4; ++mi)
                #pragma unroll
                for (int n = 0; n < 4; ++n)
                    hacc[mi][n] = __builtin_amdgcn_mfma_f32_16x16x32_bf16(
                        aw[mi], bh[n], hacc[mi][n], 0, 0, 0);
            __builtin_amdgcn_s_setprio(0);
        }

        // all waves done reading hidB (prev expert GEMM2) before overwriting
        asm volatile("s_barrier" ::: "memory");

        // epilogue1-T: v = relu(hid + b1)*c[b,e] -> bf16 hidB (b1 from LDS)
        {
            const float* b1w = (const float*)(smem + OFF_B1) + wv * 64;
            int hb0 = wv * 64 + lg * 4;
            #pragma unroll
            for (int mi = 0; mi < 4; ++mi) {
                int hb = hb0 + mi * 16;
                f32x4 b1v = *reinterpret_cast<const f32x4*>(b1w + lg * 4 + mi * 16);
                #pragma unroll
                for (int n = 0; n < 4; ++n) {
                    int b = n * 16 + l15;
                    float cbe = wc[b * WCLD + e];
                    float v0 = fmaxf(hacc[mi][n][0] + b1v[0], 0.f) * cbe;
                    float v1 = fmaxf(hacc[mi][n][1] + b1v[1], 0.f) * cbe;
                    float v2 = fmaxf(hacc[mi][n][2] + b1v[2], 0.f) * cbe;
                    float v3 = fmaxf(hacc[mi][n][3] + b1v[3], 0.f) * cbe;
                    unsigned lo = (unsigned)f2bf(v0) | ((unsigned)f2bf(v1) << 16);
                    unsigned hi = (unsigned)f2bf(v2) | ((unsigned)f2bf(v3) << 16);
                    *reinterpret_cast<uint2*>(hidB + hoff(b, hb)) = make_uint2(lo, hi);
                }
            }
        }
        asm volatile("s_waitcnt lgkmcnt(0)\n\ts_barrier" ::: "memory");

        // GEMM2-T: 8 chunks K=32 (g0,g1 prefetched during GEMM1 tail)
        #pragma unroll
        for (int gi = 0; gi < 8; ++gi) {
            const char* nsrc = (gi + 2 < 8) ? (w2e + (gi + 2) * CHK)
                                            : (w1n + (gi - 6) * CHK);
            stage4(nsrc, pw + (gi % 3) * 4096, wv, lane);   // (16+gi+2)%3 = gi%3
            WAITV(8);
            const char* pb = pw + ((gi + 1) % 3) * 4096;    // (16+gi)%3
            short8 aw[4], bh[4];
            #pragma unroll
            for (int mi = 0; mi < 4; ++mi) {
                int rp = mi * 16 + l15;
                aw[mi] = *reinterpret_cast<const short8*>(
                    pb + rp * 64 + ((lg ^ csb) << 4));
            }
            int kg = gi * 32 + lg * 8;
            #pragma unroll
            for (int n = 0; n < 4; ++n) {
                int b = n * 16 + l15;
                bh[n] = *reinterpret_cast<const short8*>(
                    hidB + b * HLD + (((kg >> 3) ^ (b & 7)) << 4));
            }
            __builtin_amdgcn_s_setprio(1);
            #pragma unroll
            for (int mi = 0; mi < 4; ++mi)
                #pragma unroll
                for (int n = 0; n < 4; ++n)
                    outacc[mi][n] = __builtin_amdgcn_mfma_f32_16x16x32_bf16(
                        aw[mi], bh[n], outacc[mi][n], 0, 0, 0);
            __builtin_amdgcn_s_setprio(0);
        }

        w1e = w1n;
    }

    // ---- final epilogue: out[b][z] = outT[z][b] + sum_e c[b,e]*b2[e,z] ----
    {
        int zb = wv * 64 + lg * 4;          // mi adds 16
        #pragma unroll
        for (int e = 0; e < 16; ++e) {
            float cbe[4];
            #pragma unroll
            for (int n = 0; n < 4; ++n) cbe[n] = wc[(n * 16 + l15) * WCLD + e];
            #pragma unroll
            for (int mi = 0; mi < 4; ++mi) {
                f32x4 b2v = *reinterpret_cast<const f32x4*>(
                    b2 + (size_t)e * Zz + zb + mi * 16);
                #pragma unroll
                for (int n = 0; n < 4; ++n) outacc[mi][n] += cbe[n] * b2v;
            }
        }
        #pragma unroll
        for (int mi = 0; mi < 4; ++mi) {
            #pragma unroll
            for (int n = 0; n < 4; ++n) {
                int b = b0 + n * 16 + l15;
                *reinterpret_cast<f32x4*>(out + (size_t)b * Zz + zb + mi * 16) =
                    outacc[mi][n];
            }
        }
    }
    // drain dangling wrap-around prefetches before wave exit
    asm volatile("s_waitcnt vmcnt(0)" ::: "memory");
}

extern "C" void kernel_launch(void* const* d_in, const int* in_sizes, int n_in,
                              void* d_out, int out_size, void* d_ws, size_t ws_size,
                              hipStream_t stream) {
    const float* h   = (const float*)d_in[0];
    const float* phi = (const float*)d_in[1];
    const float* W1  = (const float*)d_in[2];
    const float* b1  = (const float*)d_in[3];
    const float* W2  = (const float*)d_in[4];
    const float* b2  = (const float*)d_in[5];
    float* out = (float*)d_out;

    unsigned short* w1p = (unsigned short*)d_ws;                      // 4 MB packed
    unsigned short* w2p = w1p + (size_t)Ee * Hh * Dd;                 // 2 MB packed

    (void)hipFuncSetAttribute((const void*)moe_fused,
                              hipFuncAttributeMaxDynamicSharedMemorySize, SMEM_MAIN);

    transpose_pack<<<Ee * (Dd / 64) * (Hh / 64), 256, 0, stream>>>(W1, w1p, Dd, Hh);
    transpose_pack<<<Ee * (Hh / 64) * (Zz / 64), 256, 0, stream>>>(W2, w2p, Hh, Zz);

    moe_fused<<<Bsz / BT, 256, SMEM_MAIN, stream>>>(
        h, phi, b1, b2, (const char*)w1p, (const char*)w2p, out);
}

// Round 15
// 124.958 us; speedup vs baseline: 2.0846x; 1.0590x over previous
//
#include <hip/hip_runtime.h>

typedef __attribute__((ext_vector_type(8))) short short8;
typedef __attribute__((ext_vector_type(4))) float f32x4;

// Problem constants (B, D, E, S, H, Z) = (16384, 512, 16, 1, 256, 256)
constexpr int Bsz = 16384;
constexpr int Dd  = 512;
constexpr int Ee  = 16;
constexpr int Hh  = 256;
constexpr int Zz  = 256;
constexpr int BT  = 64;       // b rows per block
constexpr int WCLD = 17;      // wc padded stride
constexpr int HLD  = 544;     // hidB row stride bytes (512 + 32 pad)
constexpr int CHK  = 16384;   // weight chunk: 256 rows x 32 k bf16 = 16KB
// LDS: hA 64KB | per-wave triple bufs 4x3x4KB | hidB 34KB | wc 4.25KB | b1 1KB
constexpr int OFF_P   = 65536;
constexpr int OFF_HID = OFF_P + 4 * 3 * 4096;        // 114688
constexpr int OFF_WC  = OFF_HID + BT * HLD;          // 149504
constexpr int OFF_B1  = OFF_WC + 64 * WCLD * 4;      // 153856
constexpr int SMEM_MAIN = OFF_B1 + 1024;             // 154880 B

// counted per-wave vmcnt wait; memory clobber orders following ds_reads
#define WAITV(N) asm volatile("s_waitcnt vmcnt(" #N ")" ::: "memory")

__device__ __forceinline__ unsigned short f2bf(float f) {
    unsigned u = __float_as_uint(f);
    u += 0x7FFFu + ((u >> 16) & 1u);          // round-to-nearest-even
    return (unsigned short)(u >> 16);
}

// hidB swizzled byte offset (R10/R11-validated)
__device__ __forceinline__ int hoff(int b, int h) {
    return b * HLD + ((((h) >> 3) ^ (b & 7)) << 4) + ((h & 7) << 1);
}

// packed-weight byte offset: chunk 16KB | row*64 | col XOR | k&7 (R11-validated)
__device__ __forceinline__ size_t woff(int row, int k) {
    return (size_t)(k >> 5) * CHK + (size_t)row * 64 +
           ((((k >> 3) & 3) ^ ((row >> 1) & 3)) << 4) + ((k & 7) << 1);
}

// stage this wave's private 4KB slice of a 16KB chunk (4 x 1KB loads)
__device__ __forceinline__ void stage4(const char* chunkBase, char* ldsbuf,
                                       int wv, int lane) {
    const char* g = chunkBase + wv * 4096 + lane * 16;
    #pragma unroll
    for (int r = 0; r < 4; ++r)
        __builtin_amdgcn_global_load_lds(
            (const __attribute__((address_space(1))) void*)(g + r * 1024),
            (__attribute__((address_space(3))) void*)(ldsbuf + r * 1024), 16, 0, 0);
}

// Transpose + fp32->bf16 + pack into the chunked/swizzled image
__global__ void transpose_pack(const float* __restrict__ src,
                               unsigned short* __restrict__ dst,
                               int R, int C) {
    __shared__ float tile[64][65];
    int tilesC = C >> 6, tilesR = R >> 6;
    int bid = blockIdx.x;
    int e  = bid / (tilesR * tilesC);
    int rm = bid % (tilesR * tilesC);
    int rt = rm / tilesC;
    int ct = rm % tilesC;
    int t  = threadIdx.x;
    int c  = t & 63;
    int r0 = t >> 6;
    const float* s = src + (size_t)e * R * C + (size_t)(rt * 64) * C + ct * 64;
    #pragma unroll
    for (int i = 0; i < 16; ++i) {
        int r = r0 + i * 4;
        tile[r][c] = s[(size_t)r * C + c];
    }
    __syncthreads();
    char* dbase = (char*)dst + (size_t)e * R * C * 2;
    #pragma unroll
    for (int i = 0; i < 16; ++i) {
        int r = r0 + i * 4;
        int row_g = ct * 64 + r;        // output row (C-dim)
        int k_g   = rt * 64 + c;        // k (R-dim)
        *reinterpret_cast<unsigned short*>(dbase + woff(row_g, k_g)) =
            f2bf(tile[c][r]);
    }
}

// Fused SoftMoE, transposed-GEMM form: hidT[h][b], outT[z][b].
// 256 blocks x 256 threads (4 waves), 1 block/CU. Waves free-run through
// wave-private staged weight chunks (dist-2 counted vmcnt, NO barriers in the
// K loops); only 2 barriers/expert around the shared hidB tile.
__global__ __launch_bounds__(256, 1) void moe_fused(
    const float* __restrict__ hptr,            // [B][512] f32
    const float* __restrict__ phi,             // [512][16] f32
    const float* __restrict__ b1,              // [16][256] f32
    const float* __restrict__ b2,              // [16][256] f32
    const char* __restrict__ w1c,              // packed W1, 256KB/expert
    const char* __restrict__ w2c,              // packed W2, 128KB/expert
    float* __restrict__ out)                   // [B][256] f32
{
    extern __shared__ char smem[];
    char*  hA   = smem;                         // [64][512] bf16, XOR-swizzled
    char*  hidB = smem + OFF_HID;               // [64 b][256 h] bf16, swizzled
    float* wc   = (float*)(smem + OFF_WC);      // [64][17] softmax

    const int t    = threadIdx.x;
    const int lane = t & 63;
    const int wv   = t >> 6;          // wave 0..3: owns h/z rows [wv*64, +64)
    const int l15  = lane & 15;
    const int lg   = lane >> 4;       // 0..3
    const int b0   = blockIdx.x * BT;
    const int csb  = (l15 >> 1) & 3;  // weight col-swizzle base

    char* pw = smem + OFF_P + wv * 12288;       // this wave's 3 x 4KB buffers

    // prologue: stage expert-0 chunks 0,1 (land during h-staging + gating)
    stage4(w1c, pw, wv, lane);
    stage4(w1c + CHK, pw + 4096, wv, lane);

    // ---- stage h tile -> bf16 swizzled LDS ----
    {
        const f32x4* hsrc = reinterpret_cast<const f32x4*>(hptr + (size_t)b0 * Dd);
        #pragma unroll
        for (int i = 0; i < 32; ++i) {
            int idx = t + i * 256;
            int row = idx >> 7;
            int kc  = idx & 127;
            int k   = kc << 2;
            f32x4 v = hsrc[(size_t)row * 128 + kc];
            unsigned lo = (unsigned)f2bf(v.x) | ((unsigned)f2bf(v.y) << 16);
            unsigned hi = (unsigned)f2bf(v.z) | ((unsigned)f2bf(v.w) << 16);
            int byte = (row << 10) + (((k >> 3) ^ (row & 7)) << 4) + ((k & 7) << 1);
            *reinterpret_cast<uint2*>(hA + byte) = make_uint2(lo, hi);
        }
    }
    __syncthreads();

    // ---- gating via MFMA: 64x16 logits (waves redundant), wave 0 stores ----
    {
        f32x4 g[4];
        #pragma unroll
        for (int m = 0; m < 4; ++m) g[m] = (f32x4){0.f, 0.f, 0.f, 0.f};
        #pragma unroll
        for (int kc = 0; kc < 16; ++kc) {
            int kb = kc * 32 + lg * 8;
            short8 bfr;
            #pragma unroll
            for (int j = 0; j < 8; ++j)
                bfr[j] = (short)f2bf(phi[(size_t)(kb + j) * Ee + l15]);
            #pragma unroll
            for (int m = 0; m < 4; ++m) {
                int row = m * 16 + l15;
                short8 af = *reinterpret_cast<const short8*>(
                    hA + (row << 10) + (((kb >> 3) ^ (row & 7)) << 4));
                g[m] = __builtin_amdgcn_mfma_f32_16x16x32_bf16(af, bfr, g[m], 0, 0, 0);
            }
        }
        if (wv == 0) {
            #pragma unroll
            for (int m = 0; m < 4; ++m)
                #pragma unroll
                for (int j = 0; j < 4; ++j)
                    wc[(m * 16 + lg * 4 + j) * WCLD + l15] = g[m][j];
        }
    }
    __syncthreads();
    if (t < 64) {
        float w[16];
        float mx = -1e30f;
        #pragma unroll
        for (int e = 0; e < 16; ++e) { w[e] = wc[t * WCLD + e]; mx = fmaxf(mx, w[e]); }
        float s = 0.f;
        #pragma unroll
        for (int e = 0; e < 16; ++e) { w[e] = __expf(w[e] - mx); s += w[e]; }
        float inv = 1.f / s;
        #pragma unroll
        for (int e = 0; e < 16; ++e) wc[t * WCLD + e] = w[e] * inv;
    }
    __syncthreads();

    f32x4 outacc[4][4];
    #pragma unroll
    for (int mi = 0; mi < 4; ++mi)
        #pragma unroll
        for (int n = 0; n < 4; ++n) outacc[mi][n] = (f32x4){0.f, 0.f, 0.f, 0.f};

    const char* w1e = w1c;
    for (int e = 0; e < Ee; ++e) {
        const char* w2e = w2c + (size_t)e * (Hh * Hh * 2);
        const char* w1n = w1c + (size_t)((e + 1) & 15) * (Hh * Dd * 2);

        // b1 -> LDS (adds 1 to queue; folded into iter-0/1 waits)
        __builtin_amdgcn_global_load_lds(
            (const __attribute__((address_space(1))) void*)(b1 + (size_t)e * Hh + wv * 64 + lane),
            (__attribute__((address_space(3))) void*)(smem + OFF_B1 + wv * 256), 4, 0, 0);

        f32x4 hacc[4][4];
        #pragma unroll
        for (int mi = 0; mi < 4; ++mi)
            #pragma unroll
            for (int n = 0; n < 4; ++n) hacc[mi][n] = (f32x4){0.f, 0.f, 0.f, 0.f};

        // GEMM1-T: 16 chunks K=32, dist-2, wave-private, barrier-free.
        // Ledger: iter0 [c0,c1,b1,c2]=13 wait 9; iter1 13 wait 9;
        //         iter2 [b1,c2,c3,c4]=13 wait 8 (b1 done); steady 12 wait 8.
        #pragma unroll
        for (int ci = 0; ci < 16; ++ci) {
            const char* nsrc = (ci + 2 < 16) ? (w1e + (ci + 2) * CHK)
                                             : (w2e + (ci - 14) * CHK);
            stage4(nsrc, pw + ((ci + 2) % 3) * 4096, wv, lane);
            if (ci < 2) { WAITV(9); } else { WAITV(8); }
            const char* pb = pw + (ci % 3) * 4096;
            short8 aw[4], bh[4];
            #pragma unroll
            for (int mi = 0; mi < 4; ++mi) {
                int rp = mi * 16 + l15;
                aw[mi] = *reinterpret_cast<const short8*>(
                    pb + rp * 64 + ((lg ^ csb) << 4));
            }
            int kg = ci * 32 + lg * 8;
            #pragma unroll
            for (int n = 0; n < 4; ++n) {
                int b = n * 16 + l15;
                bh[n] = *reinterpret_cast<const short8*>(
                    hA + (b << 10) + (((kg >> 3) ^ (b & 7)) << 4));
            }
            #pragma unroll
            for (int mi = 0; mi < 4; ++mi)
                #pragma unroll
                for (int n = 0; n < 4; ++n)
                    hacc[mi][n] = __builtin_amdgcn_mfma_f32_16x16x32_bf16(
                        aw[mi], bh[n], hacc[mi][n], 0, 0, 0);
        }

        // all waves done reading hidB (prev expert GEMM2) before overwriting
        asm volatile("s_barrier" ::: "memory");

        // epilogue1-T: v = relu(hid + b1)*c[b,e] -> bf16 hidB (b1 from LDS)
        {
            const float* b1w = (const float*)(smem + OFF_B1) + wv * 64;
            int hb0 = wv * 64 + lg * 4;
            #pragma unroll
            for (int mi = 0; mi < 4; ++mi) {
                int hb = hb0 + mi * 16;
                f32x4 b1v = *reinterpret_cast<const f32x4*>(b1w + lg * 4 + mi * 16);
                #pragma unroll
                for (int n = 0; n < 4; ++n) {
                    int b = n * 16 + l15;
                    float cbe = wc[b * WCLD + e];
                    float v0 = fmaxf(hacc[mi][n][0] + b1v[0], 0.f) * cbe;
                    float v1 = fmaxf(hacc[mi][n][1] + b1v[1], 0.f) * cbe;
                    float v2 = fmaxf(hacc[mi][n][2] + b1v[2], 0.f) * cbe;
                    float v3 = fmaxf(hacc[mi][n][3] + b1v[3], 0.f) * cbe;
                    unsigned lo = (unsigned)f2bf(v0) | ((unsigned)f2bf(v1) << 16);
                    unsigned hi = (unsigned)f2bf(v2) | ((unsigned)f2bf(v3) << 16);
                    *reinterpret_cast<uint2*>(hidB + hoff(b, hb)) = make_uint2(lo, hi);
                }
            }
        }
        asm volatile("s_waitcnt lgkmcnt(0)\n\ts_barrier" ::: "memory");

        // GEMM2-T: 8 chunks K=32 (g0,g1 prefetched during GEMM1 tail)
        #pragma unroll
        for (int gi = 0; gi < 8; ++gi) {
            const char* nsrc = (gi + 2 < 8) ? (w2e + (gi + 2) * CHK)
                                            : (w1n + (gi - 6) * CHK);
            stage4(nsrc, pw + (gi % 3) * 4096, wv, lane);   // (16+gi+2)%3 = gi%3
            WAITV(8);
            const char* pb = pw + ((gi + 1) % 3) * 4096;    // (16+gi)%3
            short8 aw[4], bh[4];
            #pragma unroll
            for (int mi = 0; mi < 4; ++mi) {
                int rp = mi * 16 + l15;
                aw[mi] = *reinterpret_cast<const short8*>(
                    pb + rp * 64 + ((lg ^ csb) << 4));
            }
            int kg = gi * 32 + lg * 8;
            #pragma unroll
            for (int n = 0; n < 4; ++n) {
                int b = n * 16 + l15;
                bh[n] = *reinterpret_cast<const short8*>(
                    hidB + b * HLD + (((kg >> 3) ^ (b & 7)) << 4));
            }
            #pragma unroll
            for (int mi = 0; mi < 4; ++mi)
                #pragma unroll
                for (int n = 0; n < 4; ++n)
                    outacc[mi][n] = __builtin_amdgcn_mfma_f32_16x16x32_bf16(
                        aw[mi], bh[n], outacc[mi][n], 0, 0, 0);
        }

        w1e = w1n;
    }

    // ---- final epilogue: out[b][z] = outT[z][b] + sum_e c[b,e]*b2[e,z] ----
    {
        int zb = wv * 64 + lg * 4;          // mi adds 16
        #pragma unroll
        for (int e = 0; e < 16; ++e) {
            float cbe[4];
            #pragma unroll
            for (int n = 0; n < 4; ++n) cbe[n] = wc[(n * 16 + l15) * WCLD + e];
            #pragma unroll
            for (int mi = 0; mi < 4; ++mi) {
                f32x4 b2v = *reinterpret_cast<const f32x4*>(
                    b2 + (size_t)e * Zz + zb + mi * 16);
                #pragma unroll
                for (int n = 0; n < 4; ++n) outacc[mi][n] += cbe[n] * b2v;
            }
        }
        #pragma unroll
        for (int mi = 0; mi < 4; ++mi) {
            #pragma unroll
            for (int n = 0; n < 4; ++n) {
                int b = b0 + n * 16 + l15;
                *reinterpret_cast<f32x4*>(out + (size_t)b * Zz + zb + mi * 16) =
                    outacc[mi][n];
            }
        }
    }
    // drain dangling wrap-around prefetches before wave exit
    asm volatile("s_waitcnt vmcnt(0)" ::: "memory");
}

extern "C" void kernel_launch(void* const* d_in, const int* in_sizes, int n_in,
                              void* d_out, int out_size, void* d_ws, size_t ws_size,
                              hipStream_t stream) {
    const float* h   = (const float*)d_in[0];
    const float* phi = (const float*)d_in[1];
    const float* W1  = (const float*)d_in[2];
    const float* b1  = (const float*)d_in[3];
    const float* W2  = (const float*)d_in[4];
    const float* b2  = (const float*)d_in[5];
    float* out = (float*)d_out;

    unsigned short* w1p = (unsigned short*)d_ws;                      // 4 MB packed
    unsigned short* w2p = w1p + (size_t)Ee * Hh * Dd;                 // 2 MB packed

    (void)hipFuncSetAttribute((const void*)moe_fused,
                              hipFuncAttributeMaxDynamicSharedMemorySize, SMEM_MAIN);

    transpose_pack<<<Ee * (Dd / 64) * (Hh / 64), 256, 0, stream>>>(W1, w1p, Dd, Hh);
    transpose_pack<<<Ee * (Hh / 64) * (Zz / 64), 256, 0, stream>>>(W2, w2p, Hh, Zz);

    moe_fused<<<Bsz / BT, 256, SMEM_MAIN, stream>>>(
        h, phi, b1, b2, (const char*)w1p, (const char*)w2p, out);
}